// Round 7
// baseline (1327.437 us; speedup 1.0000x reference)
//
#include <hip/hip_runtime.h>
#include <cstdint>

// ---------------------------------------------------------------------------
// EETransformerEncoder on MI355X (gfx950).  Round 7 = R6 structure +
// vectorized prep (bf16x8 stores), Wo direct-write epilogue (no split-K
// partials), FF2 bf16 partials, cheap ln_y kernels.
// ---------------------------------------------------------------------------

typedef __bf16 bf16_t;
typedef bf16_t bf16x4 __attribute__((ext_vector_type(4)));
typedef bf16_t bf16x8 __attribute__((ext_vector_type(8)));
typedef float  f32x4  __attribute__((ext_vector_type(4)));

#define B_    8
#define T_    512
#define IDIM  1799
#define KPAD  1856        // 29*64
#define D_    256
#define H_    4
#define DK    64
#define FF_   2048
#define L_    16
#define NROW  4096        // B_*T_
#define PKROWS 2000       // 2*MAXLEN
#define NBH   32          // B_*H_
#define NSA   4           // attention s-splits

__device__ __forceinline__ f32x4 mfma16(bf16x8 a, bf16x8 b, f32x4 c) {
  return __builtin_amdgcn_mfma_f32_16x16x32_bf16(a, b, c, 0, 0, 0);
}

__device__ __forceinline__ void async_cp16(const void* g, void* l) {
  __builtin_amdgcn_global_load_lds(
      (__attribute__((address_space(1))) void*)(g),
      (__attribute__((address_space(3))) void*)(l), 16, 0, 0);
}

// ---------------------------------------------------------------------------
// prep: all weight conversions/packing, vectorized (8 elems/thread)
// ---------------------------------------------------------------------------
#define WCAT_N (L_ * 768 * 256)
#define WOB_N  (L_ * 256 * 256)
#define W1B_N  (L_ * 2048 * 256)
#define W2B_N  (L_ * 256 * 2048)
#define BCAT_N (L_ * 768)
#define PREP8  ((WCAT_N + WOB_N + W1B_N + W2B_N) / 8)

__global__ __launch_bounds__(256) void prep_all(
    const float* __restrict__ wq, const float* __restrict__ wk,
    const float* __restrict__ wv, const float* __restrict__ wo,
    const float* __restrict__ w1, const float* __restrict__ w2,
    const float* __restrict__ bq, const float* __restrict__ bk,
    const float* __restrict__ bv, bf16_t* __restrict__ wcat,
    bf16_t* __restrict__ wob, bf16_t* __restrict__ w1b,
    bf16_t* __restrict__ w2b, float* __restrict__ bcat) {
  const int stride = gridDim.x * 256;
  for (int i8 = blockIdx.x * 256 + threadIdx.x; i8 < PREP8; i8 += stride) {
    int j = i8 * 8;
    const float* src;
    bf16_t* dst;
    if (j < WCAT_N) {
      const int per_l = 768 * 256;
      int l = j / per_l, r = j - l * per_l;
      int n = r >> 8, c = r & 255;
      int sel = n >> 8, nn = n & 255;
      const float* wsrc = (sel == 0) ? wq : (sel == 1) ? wk : wv;
      src = wsrc + ((size_t)l * 256 + nn) * 256 + c;
      dst = wcat + j;
    } else {
      j -= WCAT_N;
      if (j < WOB_N) { src = wo + j; dst = wob + j; }
      else {
        j -= WOB_N;
        if (j < W1B_N) { src = w1 + j; dst = w1b + j; }
        else { j -= W1B_N; src = w2 + j; dst = w2b + j; }
      }
    }
    float4 a = ((const float4*)src)[0];
    float4 b = ((const float4*)src)[1];
    bf16x8 o = {(bf16_t)a.x, (bf16_t)a.y, (bf16_t)a.z, (bf16_t)a.w,
                (bf16_t)b.x, (bf16_t)b.y, (bf16_t)b.z, (bf16_t)b.w};
    *(bf16x8*)dst = o;
  }
  for (int i = blockIdx.x * 256 + threadIdx.x; i < BCAT_N; i += stride) {
    int l = i / 768, n = i - l * 768;
    int sel = n >> 8, nn = n & 255;
    const float* bsrc = (sel == 0) ? bq : (sel == 1) ? bk : bv;
    bcat[i] = bsrc[l * 256 + nn];
  }
}

// one block per row; pads to kdst; vector bf16x8 stores (16B aligned)
__global__ __launch_bounds__(256) void cvt_pad_row(const float* __restrict__ s,
                                                   bf16_t* __restrict__ d,
                                                   int ksrc, int kdst) {
  const int r = blockIdx.x;
  const float* sr = s + (size_t)r * ksrc;
  bf16_t* dr = d + (size_t)r * kdst;
  for (int k8 = threadIdx.x * 8; k8 < kdst; k8 += 256 * 8) {
    bf16x8 o;
#pragma unroll
    for (int i = 0; i < 8; ++i) {
      int k = k8 + i;
      o[i] = (k < ksrc) ? (bf16_t)sr[k] : (bf16_t)0.f;
    }
    *(bf16x8*)(dr + k8) = o;
  }
}

__global__ __launch_bounds__(256) void pkn_ln(const float* __restrict__ pe_k,
                                              const float* __restrict__ lnk_g,
                                              const float* __restrict__ lnk_b,
                                              bf16_t* __restrict__ out) {
  const int idx = blockIdx.x * 4 + (threadIdx.x >> 6);
  if (idx >= L_ * PKROWS) return;
  const int lane = threadIdx.x & 63;
  const int l = idx / PKROWS, r = idx - l * PKROWS;
  float v = pe_k[(size_t)r * DK + lane];
  float s = v;
#pragma unroll
  for (int o = 32; o; o >>= 1) s += __shfl_xor(s, o);
  const float mean = s * (1.f / DK);
  const float dx = v - mean;
  float q = dx * dx;
#pragma unroll
  for (int o = 32; o; o >>= 1) q += __shfl_xor(q, o);
  const float rs = rsqrtf(q * (1.f / DK) + 1e-12f);
  out[((size_t)l * PKROWS + r) * DK + lane] =
      (bf16_t)(dx * rs * lnk_g[l * DK + lane] + lnk_b[l * DK + lane]);
}

// ---------------------------------------------------------------------------
// final LayerNorm (fp32 out), one wave per row
// ---------------------------------------------------------------------------
__global__ __launch_bounds__(256) void ln_rows_f32(const float* __restrict__ src,
                                                   const float* __restrict__ g,
                                                   const float* __restrict__ b,
                                                   float* __restrict__ dst) {
  const int row = blockIdx.x * 4 + (threadIdx.x >> 6);
  const int lane = threadIdx.x & 63;
  const float4 v = ((const float4*)(src + (size_t)row * D_))[lane];
  float s = v.x + v.y + v.z + v.w;
#pragma unroll
  for (int o = 32; o; o >>= 1) s += __shfl_xor(s, o);
  const float mean = s * (1.f / D_);
  const float d0 = v.x - mean, d1 = v.y - mean, d2 = v.z - mean, d3 = v.w - mean;
  float q = d0 * d0 + d1 * d1 + d2 * d2 + d3 * d3;
#pragma unroll
  for (int o = 32; o; o >>= 1) q += __shfl_xor(q, o);
  const float rs = rsqrtf(q * (1.f / D_) + 1e-12f);
  const float4 gg = ((const float4*)g)[lane];
  const float4 bb = ((const float4*)b)[lane];
  ((float4*)(dst + (size_t)row * D_))[lane] =
      make_float4(d0 * rs * gg.x + bb.x, d1 * rs * gg.y + bb.y,
                  d2 * rs * gg.z + bb.z, d3 * rs * gg.w + bb.w);
}

// y = LN(x) (bf16), one wave per row
__global__ __launch_bounds__(256) void ln_y(const float* __restrict__ x,
                                            const float* __restrict__ g,
                                            const float* __restrict__ b,
                                            bf16_t* __restrict__ y) {
  const int row = blockIdx.x * 4 + (threadIdx.x >> 6);
  const int lane = threadIdx.x & 63;
  const size_t idx = (size_t)row * 64 + lane;
  const float4 v = ((const float4*)x)[idx];
  float s = v.x + v.y + v.z + v.w;
#pragma unroll
  for (int o = 32; o; o >>= 1) s += __shfl_xor(s, o);
  const float mean = s * (1.f / D_);
  const float d0 = v.x - mean, d1 = v.y - mean, d2 = v.z - mean, d3 = v.w - mean;
  float q = d0 * d0 + d1 * d1 + d2 * d2 + d3 * d3;
#pragma unroll
  for (int o = 32; o; o >>= 1) q += __shfl_xor(q, o);
  const float rs = rsqrtf(q * (1.f / D_) + 1e-12f);
  const float4 gg = ((const float4*)g)[lane];
  const float4 bb = ((const float4*)b)[lane];
  bf16x4 o4 = {(bf16_t)(d0 * rs * gg.x + bb.x), (bf16_t)(d1 * rs * gg.y + bb.y),
               (bf16_t)(d2 * rs * gg.z + bb.z), (bf16_t)(d3 * rs * gg.w + bb.w)};
  ((bf16x4*)y)[idx] = o4;
}

// combine FF2 bf16 split-K partials: x += sum(parts)+bias; optional y = LN(x)
template <int NS, bool WRITE_Y>
__global__ __launch_bounds__(256) void add_combine_lnb(
    const bf16_t* __restrict__ parts, const float* __restrict__ bias,
    float* __restrict__ x, const float* __restrict__ g,
    const float* __restrict__ b, bf16_t* __restrict__ y) {
  const int row = blockIdx.x * 4 + (threadIdx.x >> 6);
  const int lane = threadIdx.x & 63;
  const size_t idx = (size_t)row * 64 + lane;
  float4 v = ((const float4*)x)[idx];
#pragma unroll
  for (int p = 0; p < NS; ++p) {
    bf16x4 pv = ((const bf16x4*)parts)[(size_t)p * NROW * 64 + idx];
    v.x += (float)pv[0]; v.y += (float)pv[1];
    v.z += (float)pv[2]; v.w += (float)pv[3];
  }
  const float4 bi = ((const float4*)bias)[lane];
  v.x += bi.x; v.y += bi.y; v.z += bi.z; v.w += bi.w;
  ((float4*)x)[idx] = v;
  if (WRITE_Y) {
    float s = v.x + v.y + v.z + v.w;
#pragma unroll
    for (int o = 32; o; o >>= 1) s += __shfl_xor(s, o);
    const float mean = s * (1.f / D_);
    const float d0 = v.x - mean, d1 = v.y - mean, d2 = v.z - mean, d3 = v.w - mean;
    float q = d0 * d0 + d1 * d1 + d2 * d2 + d3 * d3;
#pragma unroll
    for (int o = 32; o; o >>= 1) q += __shfl_xor(q, o);
    const float rs = rsqrtf(q * (1.f / D_) + 1e-12f);
    const float4 gg = ((const float4*)g)[lane];
    const float4 bb = ((const float4*)b)[lane];
    bf16x4 o4 = {(bf16_t)(d0 * rs * gg.x + bb.x), (bf16_t)(d1 * rs * gg.y + bb.y),
                 (bf16_t)(d2 * rs * gg.z + bb.z), (bf16_t)(d3 * rs * gg.w + bb.w)};
    ((bf16x4*)y)[idx] = o4;
  }
}

// embed combine: x = relu(LN(sum4(parts)+bias)); y = LN1(x) bf16
__global__ __launch_bounds__(256) void embed_combine(
    const float* __restrict__ parts, const float* __restrict__ bias,
    const float* __restrict__ g0, const float* __restrict__ b0,
    const float* __restrict__ g1, const float* __restrict__ b1,
    float* __restrict__ x, bf16_t* __restrict__ y) {
  const int row = blockIdx.x * 4 + (threadIdx.x >> 6);
  const int lane = threadIdx.x & 63;
  const size_t idx = (size_t)row * 64 + lane;
  float4 v = ((const float4*)parts)[idx];
#pragma unroll
  for (int p = 1; p < 4; ++p) {
    float4 pv = ((const float4*)parts)[(size_t)p * NROW * 64 + idx];
    v.x += pv.x; v.y += pv.y; v.z += pv.z; v.w += pv.w;
  }
  const float4 bi = ((const float4*)bias)[lane];
  v.x += bi.x; v.y += bi.y; v.z += bi.z; v.w += bi.w;
  float s = v.x + v.y + v.z + v.w;
#pragma unroll
  for (int o = 32; o; o >>= 1) s += __shfl_xor(s, o);
  float mean = s * (1.f / D_);
  float d0 = v.x - mean, d1 = v.y - mean, d2 = v.z - mean, d3 = v.w - mean;
  float q = d0 * d0 + d1 * d1 + d2 * d2 + d3 * d3;
#pragma unroll
  for (int o = 32; o; o >>= 1) q += __shfl_xor(q, o);
  float rs = rsqrtf(q * (1.f / D_) + 1e-12f);
  const float4 gg = ((const float4*)g0)[lane];
  const float4 bb = ((const float4*)b0)[lane];
  float x0 = fmaxf(d0 * rs * gg.x + bb.x, 0.f);
  float x1 = fmaxf(d1 * rs * gg.y + bb.y, 0.f);
  float x2 = fmaxf(d2 * rs * gg.z + bb.z, 0.f);
  float x3 = fmaxf(d3 * rs * gg.w + bb.w, 0.f);
  ((float4*)x)[idx] = make_float4(x0, x1, x2, x3);
  s = x0 + x1 + x2 + x3;
#pragma unroll
  for (int o = 32; o; o >>= 1) s += __shfl_xor(s, o);
  mean = s * (1.f / D_);
  d0 = x0 - mean; d1 = x1 - mean; d2 = x2 - mean; d3 = x3 - mean;
  q = d0 * d0 + d1 * d1 + d2 * d2 + d3 * d3;
#pragma unroll
  for (int o = 32; o; o >>= 1) q += __shfl_xor(q, o);
  rs = rsqrtf(q * (1.f / D_) + 1e-12f);
  const float4 g1v = ((const float4*)g1)[lane];
  const float4 b1v = ((const float4*)b1)[lane];
  bf16x4 o4 = {(bf16_t)(d0 * rs * g1v.x + b1v.x), (bf16_t)(d1 * rs * g1v.y + b1v.y),
               (bf16_t)(d2 * rs * g1v.z + b1v.z), (bf16_t)(d3 * rs * g1v.w + b1v.w)};
  ((bf16x4*)y)[idx] = o4;
}

// ---------------------------------------------------------------------------
// bf16 NT GEMM, BK=64: C[M,N] = A[M,K] * B[N,K]^T, split-K via blockIdx.z.
// EP: 1 bf16 bias; 2 bf16 bias+relu; 4 f32 raw partial; 5 bf16 raw partial
// ---------------------------------------------------------------------------
template <int BM, int BN, int EP, int MINW>
__global__ __launch_bounds__(256, MINW) void gemm_bf16(
    const bf16_t* __restrict__ A, int lda, const bf16_t* __restrict__ B, int ldb,
    const float* __restrict__ bias, void* __restrict__ Cout, int ldc,
    int K, size_t zstride) {
  constexpr int HM = BM / 2, HN = BN / 2;
  constexpr int FM = HM / 16, FN = HN / 16;
  constexpr int CA = (BM * 8) / 256, CB = (BN * 8) / 256;
  __shared__ bf16_t lsA[BM * 64];
  __shared__ bf16_t lsB[BN * 64];
  const int tid = threadIdx.x;
  const int w = tid >> 6, lane = tid & 63;
  const int wm = w >> 1, wn = w & 1;
  const int lanelo = lane & 15, quad = lane >> 4;
  const int wbase = tid & ~63;
  const int m0 = blockIdx.x * BM, n0 = blockIdx.y * BN;
  const int ktiles = K >> 6;
  const int tpz = (ktiles + gridDim.z - 1) / gridDim.z;
  const int kb = blockIdx.z * tpz * 64;
  const int ke = min(K, kb + tpz * 64);
  f32x4 acc[FM][FN] = {};

  for (int kt = kb; kt < ke; kt += 64) {
    __syncthreads();
#pragma unroll
    for (int rr = 0; rr < CA; ++rr) {
      int chunk = rr * 256 + tid;
      int r = chunk >> 3, c8 = chunk & 7;
      int lg = c8 ^ (r & 7);
      async_cp16(A + (size_t)(m0 + r) * lda + kt + lg * 8,
                 lsA + (size_t)(rr * 256 + wbase) * 8);
    }
#pragma unroll
    for (int rr = 0; rr < CB; ++rr) {
      int chunk = rr * 256 + tid;
      int r = chunk >> 3, c8 = chunk & 7;
      int lg = c8 ^ (r & 7);
      async_cp16(B + (size_t)(n0 + r) * ldb + kt + lg * 8,
                 lsB + (size_t)(rr * 256 + wbase) * 8);
    }
    __syncthreads();
    bf16x8 af[FM][2], bfv[FN][2];
#pragma unroll
    for (int i = 0; i < FM; ++i) {
      int r = wm * HM + i * 16 + lanelo;
#pragma unroll
      for (int kk = 0; kk < 2; ++kk)
        af[i][kk] = *(const bf16x8*)(lsA + (size_t)(r * 8 + ((kk * 4 + quad) ^ (r & 7))) * 8);
    }
#pragma unroll
    for (int j = 0; j < FN; ++j) {
      int r = wn * HN + j * 16 + lanelo;
#pragma unroll
      for (int kk = 0; kk < 2; ++kk)
        bfv[j][kk] = *(const bf16x8*)(lsB + (size_t)(r * 8 + ((kk * 4 + quad) ^ (r & 7))) * 8);
    }
#pragma unroll
    for (int kk = 0; kk < 2; ++kk)
#pragma unroll
      for (int i = 0; i < FM; ++i)
#pragma unroll
        for (int j = 0; j < FN; ++j)
          acc[i][j] = mfma16(af[i][kk], bfv[j][kk], acc[i][j]);
  }

#pragma unroll
  for (int i = 0; i < FM; ++i) {
#pragma unroll
    for (int j = 0; j < FN; ++j) {
#pragma unroll
      for (int reg = 0; reg < 4; ++reg) {
        const int m = m0 + wm * HM + i * 16 + quad * 4 + reg;
        const int n = n0 + wn * HN + j * 16 + lanelo;
        const size_t idx = (size_t)m * ldc + n;
        if constexpr (EP == 4) {
          ((float*)Cout + (size_t)blockIdx.z * zstride)[idx] = acc[i][j][reg];
        } else if constexpr (EP == 5) {
          ((bf16_t*)Cout + (size_t)blockIdx.z * zstride)[idx] =
              (bf16_t)acc[i][j][reg];
        } else {
          float v = acc[i][j][reg] + bias[n];
          if constexpr (EP == 1) {
            ((bf16_t*)Cout)[idx] = (bf16_t)v;
          } else {
            ((bf16_t*)Cout)[idx] = (bf16_t)fmaxf(v, 0.f);
          }
        }
      }
    }
  }
}

// ---------------------------------------------------------------------------
// Wo GEMM, full K=256 loop, fused attention-split combine in A staging,
// direct epilogue x += C + bo (unique tile owner). grid (NROW/64, 2).
// ---------------------------------------------------------------------------
__global__ __launch_bounds__(256, 2) void wo_direct(
    const bf16_t* __restrict__ Opart, const float* __restrict__ mpart,
    const float* __restrict__ lpart, const bf16_t* __restrict__ B,
    const float* __restrict__ bo, float* __restrict__ x) {
  __shared__ bf16_t lsA[64 * 64];
  __shared__ bf16_t lsB[128 * 64];
  const int tid = threadIdx.x;
  const int w = tid >> 6, lane = tid & 63;
  const int wm = w >> 1, wn = w & 1;
  const int lanelo = lane & 15, quad = lane >> 4;
  const int wbase = tid & ~63;
  const int m0 = blockIdx.x * 64, n0 = blockIdx.y * 128;
  const int bb = m0 >> 9, t0 = m0 & 511;
  f32x4 acc[2][4] = {};

  for (int kt = 0; kt < 256; kt += 64) {
    __syncthreads();
    const int hh = kt >> 6;
    const int bh = bb * 4 + hh;
#pragma unroll
    for (int rr = 0; rr < 2; ++rr) {
      int chunk = rr * 256 + tid;
      int r = chunk >> 3, c8 = chunk & 7;
      int dk0 = (c8 ^ (r & 7)) * 8;
      int t = t0 + r;
      float mp[NSA], lp[NSA];
      float mmax = -__builtin_inff();
#pragma unroll
      for (int p = 0; p < NSA; ++p) {
        const size_t prow = ((size_t)p * NBH + bh) * T_ + t;
        mp[p] = mpart[prow]; lp[p] = lpart[prow];
        mmax = fmaxf(mmax, mp[p]);
      }
      float e[NSA], denom = 0.f;
#pragma unroll
      for (int p = 0; p < NSA; ++p) {
        e[p] = __expf(mp[p] - mmax);
        denom += lp[p] * e[p];
      }
      const float inv = (denom > 0.f) ? 1.f / denom : 0.f;
      float cv[8] = {};
#pragma unroll
      for (int p = 0; p < NSA; ++p) {
        const float wgt = e[p] * inv;
        bf16x8 op = *(const bf16x8*)(Opart +
            (((size_t)p * NBH + bh) * T_ + t) * 64 + dk0);
#pragma unroll
        for (int i = 0; i < 8; ++i) cv[i] += wgt * (float)op[i];
      }
      bf16x8 rv;
#pragma unroll
      for (int i = 0; i < 8; ++i) rv[i] = (bf16_t)cv[i];
      *(bf16x8*)(lsA + (size_t)chunk * 8) = rv;
    }
#pragma unroll
    for (int rr = 0; rr < 4; ++rr) {
      int chunk = rr * 256 + tid;
      int r = chunk >> 3, c8 = chunk & 7;
      int lg = c8 ^ (r & 7);
      async_cp16(B + (size_t)(n0 + r) * 256 + kt + lg * 8,
                 lsB + (size_t)(rr * 256 + wbase) * 8);
    }
    __syncthreads();
    bf16x8 af[2][2], bfv[4][2];
#pragma unroll
    for (int i = 0; i < 2; ++i) {
      int r = wm * 32 + i * 16 + lanelo;
#pragma unroll
      for (int kk = 0; kk < 2; ++kk)
        af[i][kk] = *(const bf16x8*)(lsA + (size_t)(r * 8 + ((kk * 4 + quad) ^ (r & 7))) * 8);
    }
#pragma unroll
    for (int j = 0; j < 4; ++j) {
      int r = wn * 64 + j * 16 + lanelo;
#pragma unroll
      for (int kk = 0; kk < 2; ++kk)
        bfv[j][kk] = *(const bf16x8*)(lsB + (size_t)(r * 8 + ((kk * 4 + quad) ^ (r & 7))) * 8);
    }
#pragma unroll
    for (int kk = 0; kk < 2; ++kk)
#pragma unroll
      for (int i = 0; i < 2; ++i)
#pragma unroll
        for (int j = 0; j < 4; ++j)
          acc[i][j] = mfma16(af[i][kk], bfv[j][kk], acc[i][j]);
  }

#pragma unroll
  for (int i = 0; i < 2; ++i)
#pragma unroll
    for (int j = 0; j < 4; ++j)
#pragma unroll
      for (int reg = 0; reg < 4; ++reg) {
        const int m = m0 + wm * 32 + i * 16 + quad * 4 + reg;
        const int n = n0 + wn * 64 + j * 16 + lanelo;
        const size_t idx = (size_t)m * D_ + n;
        x[idx] = x[idx] + acc[i][j][reg] + bo[n];
      }
}

// ---------------------------------------------------------------------------
// Fused flash attention w/ LDS-resident rel-pos bias, pipelined front-end.
// grid (T/64, NBH, NSA); LDS 50.5 KB -> 3 blocks/CU.
// ---------------------------------------------------------------------------
__global__ __launch_bounds__(256, 3) void attn_fused(
    const bf16_t* __restrict__ qkv, const bf16_t* __restrict__ pkn,
    const int* __restrict__ masks, bf16_t* __restrict__ Opart,
    float* __restrict__ mpart, float* __restrict__ lpart) {
  __shared__ bf16_t ls_qp[64 * 72];
  __shared__ bf16_t ls_pkr[64 * 196];
  __shared__ bf16_t ls_k[64 * 64];
  __shared__ bf16_t ls_vt[64 * 72];

  const int tid = threadIdx.x, w = tid >> 6, lane = tid & 63;
  const int lanelo = lane & 15, quad = lane >> 4;
  const int wbase = tid & ~63;
  const int t0 = blockIdx.x * 64;
  const int bh = blockIdx.y, bb = bh >> 2, h = bh & 3;
  const int z = blockIdx.z;
  const size_t rowbase = (size_t)bb * T_;
  const int jb = t0 - 128 * z + 873;

#pragma unroll
  for (int rr = 0; rr < 2; ++rr) {
    int chunk = rr * 256 + tid;
    int r = chunk >> 3, c8 = chunk & 7;
    int lg = c8 ^ (r & 7);
    async_cp16(qkv + (rowbase + t0 + r) * 768 + h * 64 + lg * 8,
               ls_qp + (size_t)(rr * 256 + wbase) * 8);
  }
#pragma unroll
  for (int rr = 0; rr < 6; ++rr) {
    int chunk = rr * 256 + tid;
    int r = chunk >> 3, c8 = chunk & 7;
    int lg = c8 ^ (r & 7);
    async_cp16(pkn + (size_t)(jb + r) * DK + lg * 8,
               ls_pkr + (size_t)(rr * 256 + wbase) * 8);
  }
  const int s0_0 = 128 * z;
#pragma unroll
  for (int rr = 0; rr < 2; ++rr) {
    int chunk = rr * 256 + tid;
    int r = chunk >> 3, c8 = chunk & 7;
    int lg = c8 ^ (r & 7);
    async_cp16(qkv + (rowbase + s0_0 + r) * 768 + 256 + h * 64 + lg * 8,
               ls_k + (size_t)(rr * 256 + wbase) * 8);
  }
#pragma unroll
  for (int c = tid; c < 64 * 8; c += 256) {
    int r = c & 63, d0 = (c >> 6) * 8;
    bf16x8 vv = *(const bf16x8*)(qkv + (rowbase + s0_0 + r) * 768 + 512 + h * 64 + d0);
#pragma unroll
    for (int i = 0; i < 8; ++i) ls_vt[(d0 + i) * 72 + r] = vv[i];
  }
  int mk[2][4];
#pragma unroll
  for (int stl = 0; stl < 2; ++stl)
#pragma unroll
    for (int nf = 0; nf < 4; ++nf)
      mk[stl][nf] = masks[bb * T_ + 128 * z + 64 * stl + nf * 16 + lanelo];
  __syncthreads();  // barrier 1

  bf16x8 qf[2];
#pragma unroll
  for (int kk = 0; kk < 2; ++kk) {
    int r = w * 16 + lanelo;
    qf[kk] = *(const bf16x8*)(ls_qp + (size_t)(r * 8 + ((kk * 4 + quad) ^ (r & 7))) * 8);
  }
  f32x4 racc[12] = {};
#pragma unroll
  for (int kk = 0; kk < 2; ++kk)
#pragma unroll
    for (int nf = 0; nf < 12; ++nf) {
      int r = nf * 16 + lanelo;
      bf16x8 bj = *(const bf16x8*)(ls_pkr + (size_t)(r * 8 + ((kk * 4 + quad) ^ (r & 7))) * 8);
      racc[nf] = mfma16(qf[kk], bj, racc[nf]);
    }
  __syncthreads();  // barrier 2
#pragma unroll
  for (int nf = 0; nf < 12; ++nf)
#pragma unroll
    for (int reg = 0; reg < 4; ++reg)
      ls_pkr[(w * 16 + quad * 4 + reg) * 196 + nf * 16 + lanelo] =
          (bf16_t)racc[nf][reg];

  f32x4 o_acc[4] = {};
  float m_run[4], l_run[4];
#pragma unroll
  for (int i = 0; i < 4; ++i) { m_run[i] = -__builtin_inff(); l_run[i] = 0.f; }

  for (int stl = 0; stl < 2; ++stl) {
    const int s0 = 128 * z + 64 * stl;
    if (stl) {
      __syncthreads();  // barrier 3
#pragma unroll
      for (int rr = 0; rr < 2; ++rr) {
        int chunk = rr * 256 + tid;
        int r = chunk >> 3, c8 = chunk & 7;
        int lg = c8 ^ (r & 7);
        async_cp16(qkv + (rowbase + s0 + r) * 768 + 256 + h * 64 + lg * 8,
                   ls_k + (size_t)(rr * 256 + wbase) * 8);
      }
#pragma unroll
      for (int c = tid; c < 64 * 8; c += 256) {
        int r = c & 63, d0 = (c >> 6) * 8;
        bf16x8 vv = *(const bf16x8*)(qkv + (rowbase + s0 + r) * 768 + 512 + h * 64 + d0);
#pragma unroll
        for (int i = 0; i < 8; ++i) ls_vt[(d0 + i) * 72 + r] = vv[i];
      }
      __syncthreads();  // barrier 4
    }

    f32x4 sacc[4] = {};
#pragma unroll
    for (int kk = 0; kk < 2; ++kk)
#pragma unroll
      for (int nf = 0; nf < 4; ++nf) {
        int r = nf * 16 + lanelo;
        bf16x8 bk = *(const bf16x8*)(ls_k + (size_t)(r * 8 + ((kk * 4 + quad) ^ (r & 7))) * 8);
        sacc[nf] = mfma16(qf[kk], bk, sacc[nf]);
      }
    float sv[4][4];
#pragma unroll
    for (int nf = 0; nf < 4; ++nf) {
      const int scol = nf * 16 + lanelo;
#pragma unroll
      for (int reg = 0; reg < 4; ++reg) {
        const int trow = w * 16 + quad * 4 + reg;
        const float bt = (float)ls_pkr[trow * 196 + (trow - scol - 64 * stl + 127)];
        sv[nf][reg] = mk[stl][nf] ? (sacc[nf][reg] + bt) * 0.125f : -3.4028235e38f;
      }
    }
    float alpha[4];
#pragma unroll
    for (int reg = 0; reg < 4; ++reg) {
      float bm = fmaxf(fmaxf(sv[0][reg], sv[1][reg]), fmaxf(sv[2][reg], sv[3][reg]));
#pragma unroll
      for (int o = 1; o < 16; o <<= 1) bm = fmaxf(bm, __shfl_xor(bm, o));
      const float mn = fmaxf(m_run[reg], bm);
      alpha[reg] = __expf(m_run[reg] - mn);
      m_run[reg] = mn;
      float rsum = 0.f;
#pragma unroll
      for (int nf = 0; nf < 4; ++nf) {
        float p = __expf(sv[nf][reg] - mn) * (mk[stl][nf] ? 1.f : 0.f);
        sv[nf][reg] = p;
        rsum += p;
      }
#pragma unroll
      for (int o = 1; o < 16; o <<= 1) rsum += __shfl_xor(rsum, o);
      l_run[reg] = l_run[reg] * alpha[reg] + rsum;
    }
#pragma unroll
    for (int nf = 0; nf < 4; ++nf)
#pragma unroll
      for (int reg = 0; reg < 4; ++reg) {
        o_acc[nf][reg] *= alpha[reg];
        ls_qp[(w * 16 + quad * 4 + reg) * 72 + nf * 16 + lanelo] = (bf16_t)sv[nf][reg];
      }
#pragma unroll
    for (int kk = 0; kk < 2; ++kk) {
      bf16x8 ap = *(const bf16x8*)&ls_qp[(w * 16 + lanelo) * 72 + kk * 32 + quad * 8];
#pragma unroll
      for (int nf = 0; nf < 4; ++nf) {
        bf16x8 bv = *(const bf16x8*)&ls_vt[(nf * 16 + lanelo) * 72 + kk * 32 + quad * 8];
        o_acc[nf] = mfma16(ap, bv, o_acc[nf]);
      }
    }
  }

#pragma unroll
  for (int reg = 0; reg < 4; ++reg) {
    const int trow = w * 16 + quad * 4 + reg;
    const size_t prow = ((size_t)z * NBH + bh) * T_ + t0 + trow;
#pragma unroll
    for (int nf = 0; nf < 4; ++nf)
      Opart[prow * 64 + nf * 16 + lanelo] = (bf16_t)o_acc[nf][reg];
    if (lanelo == 0) { mpart[prow] = m_run[reg]; lpart[prow] = l_run[reg]; }
  }
}

// ---------------------------------------------------------------------------
// host
// ---------------------------------------------------------------------------
extern "C" void kernel_launch(void* const* d_in, const int* in_sizes, int n_in,
                              void* d_out, int out_size, void* d_ws, size_t ws_size,
                              hipStream_t stream) {
  const float* xs       = (const float*)d_in[0];
  const int*   masks    = (const int*)d_in[1];
  const float* emb_w    = (const float*)d_in[2];
  const float* emb_b    = (const float*)d_in[3];
  const float* emb_g    = (const float*)d_in[4];
  const float* emb_beta = (const float*)d_in[5];
  const float* pe_k     = (const float*)d_in[6];
  const float* Wq       = (const float*)d_in[7];
  const float* bq       = (const float*)d_in[8];
  const float* Wk       = (const float*)d_in[9];
  const float* bk       = (const float*)d_in[10];
  const float* Wv       = (const float*)d_in[11];
  const float* bv       = (const float*)d_in[12];
  const float* Wo       = (const float*)d_in[13];
  const float* bo       = (const float*)d_in[14];
  const float* ln1_g    = (const float*)d_in[15];
  const float* ln1_b    = (const float*)d_in[16];
  const float* ln2_g    = (const float*)d_in[17];
  const float* ln2_b    = (const float*)d_in[18];
  const float* lnk_g    = (const float*)d_in[19];
  const float* lnk_b    = (const float*)d_in[20];
  const float* W1       = (const float*)d_in[21];
  const float* b1       = (const float*)d_in[22];
  const float* W2       = (const float*)d_in[23];
  const float* b2       = (const float*)d_in[24];
  const float* after_g  = (const float*)d_in[25];
  const float* after_b  = (const float*)d_in[26];

  char* ws = (char*)d_ws;
  size_t off = 0;
  auto take = [&](size_t bytes) -> void* {
    void* p = ws + off;
    off += (bytes + 255) & ~(size_t)255;
    return p;
  };
  bf16_t* ewb  = (bf16_t*)take((size_t)D_ * KPAD * 2);
  bf16_t* wcat = (bf16_t*)take((size_t)L_ * 768 * D_ * 2);
  float*  bcat = (float*) take((size_t)L_ * 768 * 4);
  bf16_t* wob  = (bf16_t*)take((size_t)L_ * D_ * D_ * 2);
  bf16_t* w1b  = (bf16_t*)take((size_t)L_ * FF_ * D_ * 2);
  bf16_t* w2b  = (bf16_t*)take((size_t)L_ * D_ * FF_ * 2);
  bf16_t* pknb = (bf16_t*)take((size_t)L_ * PKROWS * DK * 2);
  float*  x    = (float*) take((size_t)NROW * D_ * 4);
  bf16_t* y    = (bf16_t*)take((size_t)NROW * D_ * 2);
  bf16_t* qkv  = (bf16_t*)take((size_t)NROW * 768 * 2);
  bf16_t* hbuf = (bf16_t*)take((size_t)NROW * FF_ * 2);
  bf16_t* Opart = (bf16_t*)take((size_t)NSA * NBH * T_ * 64 * 2);
  float*  mpart = (float*)take((size_t)NSA * NBH * T_ * 4);
  float*  lpart = (float*)take((size_t)NSA * NBH * T_ * 4);
  float*  gpart = (float*)take((size_t)4 * NROW * D_ * 4);   // embed f32 partials
  bf16_t* gbart = (bf16_t*)gpart;  // FF2 bf16 partials (alias; disjoint in time)
  bf16_t* xsb  = hbuf;  // xs bf16 only needed before first FF1
  const size_t ZS = (size_t)NROW * D_;

  // prep
  cvt_pad_row<<<NROW, 256, 0, stream>>>(xs, xsb, IDIM, KPAD);
  cvt_pad_row<<<D_, 256, 0, stream>>>(emb_w, ewb, IDIM, KPAD);
  prep_all<<<2048, 256, 0, stream>>>(Wq, Wk, Wv, Wo, W1, W2, bq, bk, bv,
                                     wcat, wob, w1b, w2b, bcat);
  pkn_ln<<<(L_ * PKROWS) / 4, 256, 0, stream>>>(pe_k, lnk_g, lnk_b, pknb);

  // embed: 128x128 split-K=4 -> combine (LN+relu, then ln1 of layer 0)
  gemm_bf16<128, 128, 4, 2><<<dim3(NROW / 128, D_ / 128, 4), 256, 0, stream>>>(
      xsb, KPAD, ewb, KPAD, nullptr, gpart, D_, KPAD, ZS);
  embed_combine<<<NROW / 4, 256, 0, stream>>>(gpart, emb_b, emb_g, emb_beta,
                                              ln1_g, ln1_b, x, y);

  for (int l = 0; l < L_; ++l) {
    // QKV projection
    gemm_bf16<64, 128, 1, 3><<<dim3(NROW / 64, 768 / 128), 256, 0, stream>>>(
        y, D_, wcat + (size_t)l * 768 * D_, D_, bcat + l * 768, qkv, 768, D_, 0);
    // fused flash attention (rel-bias in LDS), s-split 4
    attn_fused<<<dim3(T_ / 64, NBH, NSA), 256, 0, stream>>>(
        qkv, pknb + (size_t)l * PKROWS * DK, masks, Opart, mpart, lpart);
    // x += combine(Opart) @ Wo^T + bo   (direct write, no partials)
    wo_direct<<<dim3(NROW / 64, D_ / 128), 256, 0, stream>>>(
        Opart, mpart, lpart, wob + (size_t)l * D_ * D_, bo + l * D_, x);
    // y = LN2(x)
    ln_y<<<NROW / 4, 256, 0, stream>>>(x, ln2_g + l * D_, ln2_b + l * D_, y);
    // FF1
    gemm_bf16<128, 128, 2, 2><<<dim3(NROW / 128, FF_ / 128), 256, 0, stream>>>(
        y, D_, w1b + (size_t)l * FF_ * D_, D_, b1 + l * FF_, hbuf, FF_, D_, 0);
    // FF2: split-K=4, bf16 partials
    gemm_bf16<128, 128, 5, 2><<<dim3(NROW / 128, D_ / 128, 4), 256, 0, stream>>>(
        hbuf, FF_, w2b + (size_t)l * D_ * FF_, FF_, nullptr, gbart, D_, FF_, ZS);
    if (l < L_ - 1) {
      add_combine_lnb<4, true><<<NROW / 4, 256, 0, stream>>>(
          gbart, b2 + l * D_, x, ln1_g + (l + 1) * D_, ln1_b + (l + 1) * D_, y);
    } else {
      add_combine_lnb<4, false><<<NROW / 4, 256, 0, stream>>>(
          gbart, b2 + l * D_, x, nullptr, nullptr, nullptr);
    }
  }
  ln_rows_f32<<<NROW / 4, 256, 0, stream>>>(x, after_g, after_b, (float*)d_out);
}